// Round 1
// baseline (1674.322 us; speedup 1.0000x reference)
//
#include <hip/hip_runtime.h>
#include <math.h>

#define B_ 256
#define N_ 200
#define D_ 128
#define H_ 8
#define KD_ 16
#define L_ 3
#define FF_ 512
#define ROWS (B_*N_)          // 51200
#define BND (ROWS*D_)         // 6,553,600 floats

// ---------------- embed: h = x @ Wemb + bemb ----------------
__global__ __launch_bounds__(256) void embed_kernel(const float* __restrict__ x,
    const float* __restrict__ Wemb, const float* __restrict__ bemb,
    float* __restrict__ h)
{
  int i4 = blockIdx.x * 256 + threadIdx.x;   // over ROWS*32 float4s
  int r  = i4 >> 5, c4 = i4 & 31;
  float x0 = x[2*r], x1 = x[2*r + 1];
  const float4 w0 = ((const float4*)Wemb)[c4];
  const float4 w1 = ((const float4*)Wemb)[32 + c4];
  const float4 bb = ((const float4*)bemb)[c4];
  float4 o;
  o.x = fmaf(x0, w0.x, fmaf(x1, w1.x, bb.x));
  o.y = fmaf(x0, w0.y, fmaf(x1, w1.y, bb.y));
  o.z = fmaf(x0, w0.z, fmaf(x1, w1.z, bb.z));
  o.w = fmaf(x0, w0.w, fmaf(x1, w1.w, bb.w));
  ((float4*)h)[i4] = o;
}

// ------------- repack Wq/Wk/Wv [L,H,D,KD] -> [L][D][H*KD] -------------
__global__ __launch_bounds__(256) void repack_w(const float* __restrict__ src,
                                                float* __restrict__ dst)
{
  int i = blockIdx.x * 256 + threadIdx.x;    // total 3*16384 exact
  int l   = i >> 14;
  int rem = i & 16383;
  int d   = rem >> 7;
  int c   = rem & 127;
  int hh  = c >> 4, kk = c & 15;
  dst[i] = src[(l << 14) + (hh << 11) + (d << 4) + kk];
}

// ---------------- tiled fp32 GEMM: C = A@W (+bias)(relu)(+resid) ----------------
template<bool BIAS, bool RELU, bool RESID>
__global__ __launch_bounds__(256) void gemm_kernel(
    const float* __restrict__ A, const float* __restrict__ W,
    const float* __restrict__ bias, const float* __restrict__ resid,
    float* __restrict__ C, int M, int K, int Nc)
{
  __shared__ __align__(16) float As[16][68];   // padded: conflict-free, 16B-aligned rows
  __shared__ __align__(16) float Bs[16][64];
  const int t  = threadIdx.x;
  const int bm = blockIdx.y * 64;
  const int bn = blockIdx.x * 64;
  const int tx = t & 15, ty = t >> 4;
  const int a_row = t >> 2, a_col = (t & 3) << 2;
  const int b_row = t >> 4, b_col = (t & 15) << 2;
  float acc[4][4] = {};
  const float* Aptr = A + (bm + a_row) * K + a_col;
  const float* Wptr = W + b_row * Nc + bn + b_col;
  for (int k0 = 0; k0 < K; k0 += 16) {
    float4 av = *(const float4*)(Aptr + k0);
    float4 bv = *(const float4*)(Wptr + k0 * Nc);
    As[a_col + 0][a_row] = av.x;
    As[a_col + 1][a_row] = av.y;
    As[a_col + 2][a_row] = av.z;
    As[a_col + 3][a_row] = av.w;
    *(float4*)&Bs[b_row][b_col] = bv;
    __syncthreads();
#pragma unroll
    for (int kk = 0; kk < 16; kk++) {
#pragma unroll
      for (int i = 0; i < 4; i++) {
        float a = As[kk][(ty << 2) + i];
#pragma unroll
        for (int j = 0; j < 4; j++)
          acc[i][j] = fmaf(a, Bs[kk][(tx << 2) + j], acc[i][j]);
      }
    }
    __syncthreads();
  }
#pragma unroll
  for (int i = 0; i < 4; i++) {
    int row = bm + (ty << 2) + i;
    float4 v = { acc[i][0], acc[i][1], acc[i][2], acc[i][3] };
    if (BIAS) {
      const float4 bb = *(const float4*)&bias[bn + (tx << 2)];
      v.x += bb.x; v.y += bb.y; v.z += bb.z; v.w += bb.w;
    }
    if (RELU) {
      v.x = fmaxf(v.x, 0.f); v.y = fmaxf(v.y, 0.f);
      v.z = fmaxf(v.z, 0.f); v.w = fmaxf(v.w, 0.f);
    }
    if (RESID) {
      const float4 r = *(const float4*)&resid[row * Nc + bn + (tx << 2)];
      v.x += r.x; v.y += r.y; v.z += r.z; v.w += r.w;
    }
    *(float4*)&C[row * Nc + bn + (tx << 2)] = v;
  }
}

// ---------------- fused attention, one block per (b, head) ----------------
__global__ __launch_bounds__(256) void attn_kernel(const float* __restrict__ Q,
    const float* __restrict__ K, const float* __restrict__ V,
    float* __restrict__ O)
{
  __shared__ __align__(16) float Ks[N_][KD_];
  __shared__ __align__(16) float Vs[N_][KD_];
  const int b  = blockIdx.x >> 3;
  const int hh = blockIdx.x & 7;
  const int t  = threadIdx.x;
  const int base = b * N_ * D_ + hh * KD_;
  for (int i = t; i < N_ * 4; i += 256) {
    int n = i >> 2, q4 = i & 3;
    ((float4*)&Ks[n][0])[q4] = *(const float4*)&K[base + n * D_ + q4 * 4];
    ((float4*)&Vs[n][0])[q4] = *(const float4*)&V[base + n * D_ + q4 * 4];
  }
  __syncthreads();
  if (t < N_) {
    float q[KD_];
#pragma unroll
    for (int j = 0; j < 4; j++) {
      float4 v4 = *(const float4*)&Q[base + t * D_ + j * 4];
      q[j*4+0] = v4.x; q[j*4+1] = v4.y; q[j*4+2] = v4.z; q[j*4+3] = v4.w;
    }
    float m = -1e30f, l = 0.f;
    float o[KD_] = {};
    for (int n = 0; n < N_; n++) {
      float s = 0.f;
#pragma unroll
      for (int kk = 0; kk < KD_; kk++) s = fmaf(q[kk], Ks[n][kk], s);
      s *= 0.25f;                       // 1/sqrt(16)
      float mn   = fmaxf(m, s);
      float corr = __expf(m - mn);
      float p    = __expf(s - mn);
      l = fmaf(l, corr, p);
#pragma unroll
      for (int kk = 0; kk < KD_; kk++)
        o[kk] = fmaf(o[kk], corr, p * Vs[n][kk]);
      m = mn;
    }
    float inv = 1.f / l;
#pragma unroll
    for (int j = 0; j < 4; j++) {
      float4 v4 = { o[j*4+0]*inv, o[j*4+1]*inv, o[j*4+2]*inv, o[j*4+3]*inv };
      *(float4*)&O[base + t * D_ + j * 4] = v4;
    }
  }
}

// ---------------- BatchNorm: stage 1 partial sums ----------------
__global__ __launch_bounds__(256) void bn_partial(const float* __restrict__ h,
    float* __restrict__ psum, float* __restrict__ psq)
{
  __shared__ float ss[256], qq[256];
  int t = threadIdx.x;
  int c = t & 127, half = t >> 7;
  int r0 = blockIdx.x * 128;
  float s = 0.f, q = 0.f;
  for (int r = r0 + half; r < r0 + 128; r += 2) {
    float v = h[r * D_ + c];
    s += v;
    q = fmaf(v, v, q);
  }
  ss[t] = s; qq[t] = q;
  __syncthreads();
  if (t < 128) {
    psum[blockIdx.x * 128 + t] = ss[t] + ss[t + 128];
    psq [blockIdx.x * 128 + t] = qq[t] + qq[t + 128];
  }
}

// ---------------- BatchNorm: stage 2 finalize into folded scale/shift ----------------
__global__ __launch_bounds__(128) void bn_finalize(const float* __restrict__ psum,
    const float* __restrict__ psq, const float* __restrict__ g,
    const float* __restrict__ bta, float* __restrict__ scale,
    float* __restrict__ shift)
{
  int c = threadIdx.x;
  float s = 0.f, q = 0.f;
  for (int i = 0; i < 400; i++) { s += psum[i * 128 + c]; q += psq[i * 128 + c]; }
  const float invM = 1.f / 51200.f;
  float m  = s * invM;
  float v  = fmaf(q, invM, -m * m);     // biased variance
  float r  = rsqrtf(v + 1e-5f);
  float sc = r * g[c];
  scale[c] = sc;
  shift[c] = fmaf(-m, sc, bta[c]);
}

// ---------------- BatchNorm apply: out = in*scale + shift ----------------
__global__ __launch_bounds__(256) void bn_apply(const float* __restrict__ in,
    const float* __restrict__ scale, const float* __restrict__ shift,
    float* __restrict__ out)
{
  int i4 = blockIdx.x * 256 + threadIdx.x;   // ROWS*32 exact
  int c4 = i4 & 31;
  float4 v  = ((const float4*)in)[i4];
  float4 sc = ((const float4*)scale)[c4];
  float4 sh = ((const float4*)shift)[c4];
  v.x = fmaf(v.x, sc.x, sh.x);
  v.y = fmaf(v.y, sc.y, sh.y);
  v.z = fmaf(v.z, sc.z, sh.z);
  v.w = fmaf(v.w, sc.w, sh.w);
  ((float4*)out)[i4] = v;
}

// ---------------- final mean over N ----------------
__global__ __launch_bounds__(128) void mean_kernel(const float* __restrict__ h,
                                                   float* __restrict__ out)
{
  int b = blockIdx.x, d = threadIdx.x;
  const float* p = h + b * N_ * D_ + d;
  float s = 0.f;
  for (int n = 0; n < N_; n++) s += p[n * D_];
  out[b * D_ + d] = s * (1.f / N_);
}

extern "C" void kernel_launch(void* const* d_in, const int* in_sizes, int n_in,
                              void* d_out, int out_size, void* d_ws, size_t ws_size,
                              hipStream_t stream)
{
  const float* x    = (const float*)d_in[0];
  const float* Wemb = (const float*)d_in[1];
  const float* bemb = (const float*)d_in[2];
  const float* Wq   = (const float*)d_in[3];
  const float* Wk   = (const float*)d_in[4];
  const float* Wv   = (const float*)d_in[5];
  const float* Wo   = (const float*)d_in[6];
  const float* bn1g = (const float*)d_in[7];
  const float* bn1b = (const float*)d_in[8];
  const float* W1   = (const float*)d_in[9];
  const float* b1   = (const float*)d_in[10];
  const float* W2   = (const float*)d_in[11];
  const float* b2   = (const float*)d_in[12];
  const float* bn2g = (const float*)d_in[13];
  const float* bn2b = (const float*)d_in[14];
  float* out = (float*)d_out;

  float* ws  = (float*)d_ws;
  float* h   = ws;               // BND floats
  float* big = ws + BND;         // 4*BND floats: Q|K|V|heads, later FFN hidden
  float* qb = big, *kb = big + BND, *vb = big + 2*(size_t)BND, *hd = big + 3*(size_t)BND;
  float* wqs  = ws + 5*(size_t)BND;
  float* wks  = wqs + 3*16384;
  float* wvs  = wks + 3*16384;
  float* psum = wvs + 3*16384;
  float* psq  = psum + 51200;
  float* scale = psq + 51200;
  float* shift = scale + 128;

  embed_kernel<<<6400, 256, 0, stream>>>(x, Wemb, bemb, h);
  repack_w<<<192, 256, 0, stream>>>(Wq, wqs);
  repack_w<<<192, 256, 0, stream>>>(Wk, wks);
  repack_w<<<192, 256, 0, stream>>>(Wv, wvs);

  for (int l = 0; l < L_; l++) {
    const float* wq_l = wqs + l*16384;
    const float* wk_l = wks + l*16384;
    const float* wv_l = wvs + l*16384;
    const float* wo_l = Wo + l*16384;          // [H*KD, D] row-major already
    const float* w1_l = W1 + l*D_*FF_;
    const float* b1_l = b1 + l*FF_;
    const float* w2_l = W2 + l*FF_*D_;
    const float* b2_l = b2 + l*D_;
    dim3 g2(2, 800), g8(8, 800);

    // QKV projections
    gemm_kernel<false,false,false><<<g2, 256, 0, stream>>>(h, wq_l, nullptr, nullptr, qb, ROWS, D_, D_);
    gemm_kernel<false,false,false><<<g2, 256, 0, stream>>>(h, wk_l, nullptr, nullptr, kb, ROWS, D_, D_);
    gemm_kernel<false,false,false><<<g2, 256, 0, stream>>>(h, wv_l, nullptr, nullptr, vb, ROWS, D_, D_);
    // fused attention per (b, head)
    attn_kernel<<<B_*H_, 256, 0, stream>>>(qb, kb, vb, hd);
    // output projection + residual: h = h + heads @ Wo
    gemm_kernel<false,false,true><<<g2, 256, 0, stream>>>(hd, wo_l, nullptr, h, h, ROWS, D_, D_);
    // BN1
    bn_partial<<<400, 256, 0, stream>>>(h, psum, psq);
    bn_finalize<<<1, 128, 0, stream>>>(psum, psq, bn1g + l*D_, bn1b + l*D_, scale, shift);
    bn_apply<<<6400, 256, 0, stream>>>(h, scale, shift, h);
    // FFN
    gemm_kernel<true,true,false><<<g8, 256, 0, stream>>>(h, w1_l, b1_l, nullptr, big, ROWS, D_, FF_);
    gemm_kernel<true,false,true><<<g2, 256, 0, stream>>>(big, w2_l, b2_l, h, h, ROWS, FF_, D_);
    // BN2
    bn_partial<<<400, 256, 0, stream>>>(h, psum, psq);
    bn_finalize<<<1, 128, 0, stream>>>(psum, psq, bn2g + l*D_, bn2b + l*D_, scale, shift);
    float* dst = (l == L_ - 1) ? out : h;
    bn_apply<<<6400, 256, 0, stream>>>(h, scale, shift, dst);
  }

  mean_kernel<<<B_, 128, 0, stream>>>(out, out + BND);
}

// Round 3
// 942.016 us; speedup vs baseline: 1.7774x; 1.7774x over previous
//
#include <hip/hip_runtime.h>
#include <math.h>

#define B_ 256
#define N_ 200
#define D_ 128
#define H_ 8
#define KD_ 16
#define L_ 3
#define FF_ 512
#define ROWS (B_*N_)          // 51200
#define BND (ROWS*D_)         // 6,553,600

typedef __bf16 bf16x8 __attribute__((ext_vector_type(8)));
typedef float f32x4 __attribute__((ext_vector_type(4)));

__device__ __forceinline__ ushort f2bf(float f) {
  union { float f; unsigned u; } v; v.f = f;
  unsigned r = v.u + 0x7fffu + ((v.u >> 16) & 1u);
  return (ushort)(r >> 16);
}
__device__ __forceinline__ float bf2f(ushort h) {
  union { unsigned u; float f; } v; v.u = ((unsigned)h) << 16; return v.f;
}
__device__ __forceinline__ void split2(float f, ushort& hi, ushort& lo) {
  hi = f2bf(f);
  lo = f2bf(f - bf2f(hi));
}

// ---------------- embed: h = x @ Wemb + bemb -> h fp32 + hi/lo bf16 ----------------
__global__ __launch_bounds__(256) void embed_kernel(const float* __restrict__ x,
    const float* __restrict__ Wemb, const float* __restrict__ bemb,
    float* __restrict__ h, ushort* __restrict__ hhi, ushort* __restrict__ hlo)
{
  int i4 = blockIdx.x * 256 + threadIdx.x;   // ROWS*32 float4s
  int r  = i4 >> 5, c4 = i4 & 31;
  float x0 = x[2*r], x1 = x[2*r + 1];
  const float4 w0 = ((const float4*)Wemb)[c4];
  const float4 w1 = ((const float4*)Wemb)[32 + c4];
  const float4 bb = ((const float4*)bemb)[c4];
  float o[4];
  o[0] = fmaf(x0, w0.x, fmaf(x1, w1.x, bb.x));
  o[1] = fmaf(x0, w0.y, fmaf(x1, w1.y, bb.y));
  o[2] = fmaf(x0, w0.z, fmaf(x1, w1.z, bb.z));
  o[3] = fmaf(x0, w0.w, fmaf(x1, w1.w, bb.w));
  float4 of = { o[0], o[1], o[2], o[3] };
  ((float4*)h)[i4] = of;
  ushort hi[4], lo[4];
#pragma unroll
  for (int k = 0; k < 4; k++) split2(o[k], hi[k], lo[k]);
  uint2 ph, pl;
  ph.x = (uint)hi[0] | ((uint)hi[1] << 16);
  ph.y = (uint)hi[2] | ((uint)hi[3] << 16);
  pl.x = (uint)lo[0] | ((uint)lo[1] << 16);
  pl.y = (uint)lo[2] | ((uint)lo[3] << 16);
  ((uint2*)hhi)[i4] = ph;
  ((uint2*)hlo)[i4] = pl;
}

// ------------- weight transposes -> bf16 hi/lo [N][K] -------------
__global__ __launch_bounds__(256) void t_qkv(const float* __restrict__ Wq,
    const float* __restrict__ Wk, const float* __restrict__ Wv,
    ushort* __restrict__ dhi, ushort* __restrict__ dlo)
{
  int i = blockIdx.x * 256 + threadIdx.x;     // L*384*128 = 147456 exact
  int l = i / 49152, r = i % 49152;
  int n = r >> 7, k = r & 127;
  int which = n >> 7, hh = (n >> 4) & 7, kd = n & 15;
  const float* src = (which == 0) ? Wq : (which == 1) ? Wk : Wv;
  float w = src[l*16384 + hh*2048 + k*16 + kd];
  split2(w, dhi[i], dlo[i]);
}
__global__ __launch_bounds__(256) void t_wo(const float* __restrict__ Wo,
    ushort* __restrict__ dhi, ushort* __restrict__ dlo)
{
  int i = blockIdx.x * 256 + threadIdx.x;     // L*128*128 = 49152 exact
  int l = i / 16384, r = i % 16384;
  int n = r >> 7, k = r & 127;
  int hh = k >> 4, kd = k & 15;
  float w = Wo[l*16384 + hh*2048 + kd*128 + n];
  split2(w, dhi[i], dlo[i]);
}
__global__ __launch_bounds__(256) void t_w1(const float* __restrict__ W1,
    ushort* __restrict__ dhi, ushort* __restrict__ dlo)
{
  int i = blockIdx.x * 256 + threadIdx.x;     // L*512*128 = 196608 exact
  int l = i / 65536, r = i % 65536;
  int f = r >> 7, d = r & 127;
  float w = W1[l*65536 + d*512 + f];
  split2(w, dhi[i], dlo[i]);
}
__global__ __launch_bounds__(256) void t_w2(const float* __restrict__ W2,
    ushort* __restrict__ dhi, ushort* __restrict__ dlo)
{
  int i = blockIdx.x * 256 + threadIdx.x;     // L*128*512 = 196608 exact
  int l = i / 65536, r = i % 65536;
  int d = r >> 9, f = r & 511;
  float w = W2[l*65536 + f*128 + d];
  split2(w, dhi[i], dlo[i]);
}

// ---------------- split-bf16 MFMA GEMM: C = A@W to ~fp32 accuracy ----------------
// A, W given as bf16 hi/lo pairs, both K-major ([M][K] / [N][K]).
// C = Ahi@Whi + Alo@Whi + Ahi@Wlo  (+bias)(relu)(+resid)
// OUT_HL: write C as bf16 hi/lo pair; else fp32.
// STATS: per-block column sum/sumsq -> psum/psq[blockIdx.y*128+c] (needs gridDim.x==1).
template<int K, bool BIAS, bool RELU, bool RESID, bool OUT_HL, bool STATS>
__global__ __launch_bounds__(256, 2) void gemm_mfma(
    const ushort* __restrict__ Ahi, const ushort* __restrict__ Alo,
    const ushort* __restrict__ Whi, const ushort* __restrict__ Wlo,
    const float* __restrict__ bias, const float* __restrict__ resid,
    float* __restrict__ Cf, ushort* __restrict__ Chi, ushort* __restrict__ Clo,
    float* __restrict__ psum, float* __restrict__ psq, int Ntot)
{
  __shared__ ushort AhiS[128*64];
  __shared__ ushort AloS[128*64];
  __shared__ ushort BhiS[128*64];
  __shared__ ushort BloS[128*64];
  const int t    = threadIdx.x;
  const int bm   = blockIdx.y * 128;
  const int bn   = blockIdx.x * 128;
  const int lane = t & 63;
  const int w    = t >> 6, wm = w >> 1, wn = w & 1;
  const int quad = lane >> 4, l15 = lane & 15;

  f32x4 acc[4][4];
#pragma unroll
  for (int i = 0; i < 4; i++)
#pragma unroll
    for (int j = 0; j < 4; j++) acc[i][j] = (f32x4){0.f, 0.f, 0.f, 0.f};

  const ushort* AhiB = Ahi + (size_t)bm * K;
  const ushort* AloB = Alo + (size_t)bm * K;
  const ushort* BhiB = Whi + (size_t)bn * K;
  const ushort* BloB = Wlo + (size_t)bn * K;

  for (int k0 = 0; k0 < K; k0 += 64) {
    // stage 128 rows x 64 k; LDS [row][c], c = k8 ^ (row&7) (XOR swizzle)
#pragma unroll
    for (int i = 0; i < 4; i++) {
      int idx = i * 256 + t;
      int row = idx >> 3, c = idx & 7;
      int k8  = c ^ (row & 7);
      size_t off = (size_t)row * K + k0 + k8 * 8;
      ((uint4*)AhiS)[idx] = *(const uint4*)(AhiB + off);
      ((uint4*)AloS)[idx] = *(const uint4*)(AloB + off);
      ((uint4*)BhiS)[idx] = *(const uint4*)(BhiB + off);
      ((uint4*)BloS)[idx] = *(const uint4*)(BloB + off);
    }
    __syncthreads();
#pragma unroll
    for (int ks = 0; ks < 2; ks++) {
      bf16x8 ah[4], al[4], bh[4], bl[4];
#pragma unroll
      for (int i = 0; i < 4; i++) {
        int row = wm * 64 + i * 16 + l15;
        int k8  = ks * 4 + quad;
        int ci  = k8 ^ (row & 7);
        ah[i] = ((const bf16x8*)AhiS)[row * 8 + ci];
        al[i] = ((const bf16x8*)AloS)[row * 8 + ci];
        int nrow = wn * 64 + i * 16 + l15;
        int cj   = k8 ^ (nrow & 7);
        bh[i] = ((const bf16x8*)BhiS)[nrow * 8 + cj];
        bl[i] = ((const bf16x8*)BloS)[nrow * 8 + cj];
      }
#pragma unroll
      for (int i = 0; i < 4; i++)
#pragma unroll
        for (int j = 0; j < 4; j++) {
          acc[i][j] = __builtin_amdgcn_mfma_f32_16x16x32_bf16(al[i], bh[j], acc[i][j], 0, 0, 0);
          acc[i][j] = __builtin_amdgcn_mfma_f32_16x16x32_bf16(ah[i], bl[j], acc[i][j], 0, 0, 0);
          acc[i][j] = __builtin_amdgcn_mfma_f32_16x16x32_bf16(ah[i], bh[j], acc[i][j], 0, 0, 0);
        }
    }
    __syncthreads();
  }

  float bv[4];
  if (BIAS) {
#pragma unroll
    for (int j = 0; j < 4; j++) bv[j] = bias[bn + wn*64 + j*16 + l15];
  }
  float sj[4] = {0.f,0.f,0.f,0.f}, qj[4] = {0.f,0.f,0.f,0.f};
#pragma unroll
  for (int i = 0; i < 4; i++) {
#pragma unroll
    for (int r = 0; r < 4; r++) {
      int row = bm + wm*64 + i*16 + quad*4 + r;
#pragma unroll
      for (int j = 0; j < 4; j++) {
        int col = bn + wn*64 + j*16 + l15;
        float v = acc[i][j][r];
        if (BIAS)  v += bv[j];
        if (RELU)  v = fmaxf(v, 0.f);
        if (RESID) v += resid[(size_t)row * Ntot + col];
        if (OUT_HL) {
          ushort hi, lo;
          split2(v, hi, lo);
          Chi[(size_t)row * Ntot + col] = hi;
          Clo[(size_t)row * Ntot + col] = lo;
        } else {
          Cf[(size_t)row * Ntot + col] = v;
        }
        if (STATS) { sj[j] += v; qj[j] = fmaf(v, v, qj[j]); }
      }
    }
  }
  if (STATS) {
#pragma unroll
    for (int j = 0; j < 4; j++) {
      sj[j] += __shfl_xor(sj[j], 16); sj[j] += __shfl_xor(sj[j], 32);
      qj[j] += __shfl_xor(qj[j], 16); qj[j] += __shfl_xor(qj[j], 32);
    }
    float* ssum = (float*)AhiS;      // reuse LDS (k-loop ended with barrier)
    float* ssq  = ssum + 128;
    if (t < 128) { ssum[t] = 0.f; ssq[t] = 0.f; }
    __syncthreads();
    if (quad == 0) {
#pragma unroll
      for (int j = 0; j < 4; j++) {
        int col = wn*64 + j*16 + l15;
        atomicAdd(&ssum[col], sj[j]);
        atomicAdd(&ssq[col],  qj[j]);
      }
    }
    __syncthreads();
    if (t < 128) {
      psum[blockIdx.y * 128 + t] = ssum[t];
      psq [blockIdx.y * 128 + t] = ssq[t];
    }
  }
}

// ---------------- fused attention, chunked online softmax, hi/lo bf16 out ----------------
__global__ __launch_bounds__(256) void attn_kernel(const float* __restrict__ qkv,
    ushort* __restrict__ Ohi, ushort* __restrict__ Olo)
{
  __shared__ __align__(16) float Ks[N_][KD_];
  __shared__ __align__(16) float Vs[N_][KD_];
  const int b  = blockIdx.x >> 3;
  const int hh = blockIdx.x & 7;
  const int t  = threadIdx.x;
  const float* basep = qkv + (size_t)b * N_ * 384;
  for (int i = t; i < N_ * 8; i += 256) {
    int n = i >> 3, q4 = i & 7;
    if (q4 < 4)
      ((float4*)&Ks[n][0])[q4]     = *(const float4*)(basep + n*384 + 128 + hh*16 + q4*4);
    else
      ((float4*)&Vs[n][0])[q4 - 4] = *(const float4*)(basep + n*384 + 256 + hh*16 + (q4-4)*4);
  }
  __syncthreads();
  if (t < N_) {
    float q[KD_];
#pragma unroll
    for (int j4 = 0; j4 < 4; j4++) {
      float4 v4 = *(const float4*)(basep + t*384 + hh*16 + j4*4);
      q[j4*4+0] = v4.x; q[j4*4+1] = v4.y; q[j4*4+2] = v4.z; q[j4*4+3] = v4.w;
    }
    float m = -1e30f, l = 0.f;
    float o[KD_] = {0.f};
    for (int c0 = 0; c0 < N_; c0 += 40) {
      float s[40];
      float cmax = -1e30f;
#pragma unroll
      for (int j = 0; j < 40; j++) {
        const float4* kr = (const float4*)&Ks[c0 + j][0];
        float4 k0 = kr[0], k1 = kr[1], k2 = kr[2], k3 = kr[3];
        float a = 0.f;
        a = fmaf(q[0],  k0.x, a); a = fmaf(q[1],  k0.y, a);
        a = fmaf(q[2],  k0.z, a); a = fmaf(q[3],  k0.w, a);
        a = fmaf(q[4],  k1.x, a); a = fmaf(q[5],  k1.y, a);
        a = fmaf(q[6],  k1.z, a); a = fmaf(q[7],  k1.w, a);
        a = fmaf(q[8],  k2.x, a); a = fmaf(q[9],  k2.y, a);
        a = fmaf(q[10], k2.z, a); a = fmaf(q[11], k2.w, a);
        a = fmaf(q[12], k3.x, a); a = fmaf(q[13], k3.y, a);
        a = fmaf(q[14], k3.z, a); a = fmaf(q[15], k3.w, a);
        a *= 0.25f;                       // 1/sqrt(16)
        s[j] = a;
        cmax = fmaxf(cmax, a);
      }
      float mn   = fmaxf(m, cmax);
      float corr = __expf(m - mn);
      l *= corr;
#pragma unroll
      for (int kk = 0; kk < KD_; kk++) o[kk] *= corr;
#pragma unroll
      for (int j = 0; j < 40; j++) {
        float p = __expf(s[j] - mn);
        l += p;
        const float4* vr = (const float4*)&Vs[c0 + j][0];
        float4 v0 = vr[0], v1 = vr[1], v2 = vr[2], v3 = vr[3];
        o[0]  = fmaf(p, v0.x, o[0]);  o[1]  = fmaf(p, v0.y, o[1]);
        o[2]  = fmaf(p, v0.z, o[2]);  o[3]  = fmaf(p, v0.w, o[3]);
        o[4]  = fmaf(p, v1.x, o[4]);  o[5]  = fmaf(p, v1.y, o[5]);
        o[6]  = fmaf(p, v1.z, o[6]);  o[7]  = fmaf(p, v1.w, o[7]);
        o[8]  = fmaf(p, v2.x, o[8]);  o[9]  = fmaf(p, v2.y, o[9]);
        o[10] = fmaf(p, v2.z, o[10]); o[11] = fmaf(p, v2.w, o[11]);
        o[12] = fmaf(p, v3.x, o[12]); o[13] = fmaf(p, v3.y, o[13]);
        o[14] = fmaf(p, v3.z, o[14]); o[15] = fmaf(p, v3.w, o[15]);
      }
      m = mn;
    }
    float inv = 1.f / l;
    ushort hi[16], lo[16];
#pragma unroll
    for (int kk = 0; kk < KD_; kk++) split2(o[kk] * inv, hi[kk], lo[kk]);
    size_t obase = ((size_t)(b * N_ + t)) * 128 + hh * 16;
    uint4 ph0, ph1, pl0, pl1;
    ph0.x = (uint)hi[0]  | ((uint)hi[1]  << 16); ph0.y = (uint)hi[2]  | ((uint)hi[3]  << 16);
    ph0.z = (uint)hi[4]  | ((uint)hi[5]  << 16); ph0.w = (uint)hi[6]  | ((uint)hi[7]  << 16);
    ph1.x = (uint)hi[8]  | ((uint)hi[9]  << 16); ph1.y = (uint)hi[10] | ((uint)hi[11] << 16);
    ph1.z = (uint)hi[12] | ((uint)hi[13] << 16); ph1.w = (uint)hi[14] | ((uint)hi[15] << 16);
    pl0.x = (uint)lo[0]  | ((uint)lo[1]  << 16); pl0.y = (uint)lo[2]  | ((uint)lo[3]  << 16);
    pl0.z = (uint)lo[4]  | ((uint)lo[5]  << 16); pl0.w = (uint)lo[6]  | ((uint)lo[7]  << 16);
    pl1.x = (uint)lo[8]  | ((uint)lo[9]  << 16); pl1.y = (uint)lo[10] | ((uint)lo[11] << 16);
    pl1.z = (uint)lo[12] | ((uint)lo[13] << 16); pl1.w = (uint)lo[14] | ((uint)lo[15] << 16);
    ((uint4*)(Ohi + obase))[0] = ph0;
    ((uint4*)(Ohi + obase))[1] = ph1;
    ((uint4*)(Olo + obase))[0] = pl0;
    ((uint4*)(Olo + obase))[1] = pl1;
  }
}

// ---------------- BN finalize (reduce 400 partials) ----------------
__global__ __launch_bounds__(128) void bn_finalize(const float* __restrict__ psum,
    const float* __restrict__ psq, const float* __restrict__ g,
    const float* __restrict__ bta, float* __restrict__ scale, float* __restrict__ shift)
{
  int c = threadIdx.x;
  float s = 0.f, q = 0.f;
  for (int i = 0; i < 400; i++) { s += psum[i*128 + c]; q += psq[i*128 + c]; }
  const float invM = 1.f / 51200.f;
  float m  = s * invM;
  float v  = fmaf(q, invM, -m * m);
  float r  = rsqrtf(v + 1e-5f);
  float sc = r * g[c];
  scale[c] = sc;
  shift[c] = fmaf(-m, sc, bta[c]);
}

// ---------------- BN apply: fp32 out + hi/lo bf16 ----------------
__global__ __launch_bounds__(256) void bn_apply(const float* __restrict__ in,
    const float* __restrict__ scale, const float* __restrict__ shift,
    float* __restrict__ outf, ushort* __restrict__ outhi, ushort* __restrict__ outlo)
{
  int i4 = blockIdx.x * 256 + threadIdx.x;   // ROWS*32 exact
  int c4 = i4 & 31;
  float4 v  = ((const float4*)in)[i4];
  float4 sc = ((const float4*)scale)[c4];
  float4 sh = ((const float4*)shift)[c4];
  float o[4];
  o[0] = fmaf(v.x, sc.x, sh.x);
  o[1] = fmaf(v.y, sc.y, sh.y);
  o[2] = fmaf(v.z, sc.z, sh.z);
  o[3] = fmaf(v.w, sc.w, sh.w);
  float4 of = { o[0], o[1], o[2], o[3] };
  ((float4*)outf)[i4] = of;
  ushort hi[4], lo[4];
#pragma unroll
  for (int k = 0; k < 4; k++) split2(o[k], hi[k], lo[k]);
  uint2 ph, pl;
  ph.x = (uint)hi[0] | ((uint)hi[1] << 16);
  ph.y = (uint)hi[2] | ((uint)hi[3] << 16);
  pl.x = (uint)lo[0] | ((uint)lo[1] << 16);
  pl.y = (uint)lo[2] | ((uint)lo[3] << 16);
  ((uint2*)outhi)[i4] = ph;
  ((uint2*)outlo)[i4] = pl;
}

// ---------------- final mean over N ----------------
__global__ __launch_bounds__(128) void mean_kernel(const float* __restrict__ h,
                                                   float* __restrict__ out)
{
  int b = blockIdx.x, d = threadIdx.x;
  const float* p = h + (size_t)b * N_ * D_ + d;
  float s = 0.f;
  for (int n = 0; n < N_; n++) s += p[n * D_];
  out[b * D_ + d] = s * (1.f / N_);
}

extern "C" void kernel_launch(void* const* d_in, const int* in_sizes, int n_in,
                              void* d_out, int out_size, void* d_ws, size_t ws_size,
                              hipStream_t stream)
{
  const float* x    = (const float*)d_in[0];
  const float* Wemb = (const float*)d_in[1];
  const float* bemb = (const float*)d_in[2];
  const float* Wq   = (const float*)d_in[3];
  const float* Wk   = (const float*)d_in[4];
  const float* Wv   = (const float*)d_in[5];
  const float* Wo   = (const float*)d_in[6];
  const float* bn1g = (const float*)d_in[7];
  const float* bn1b = (const float*)d_in[8];
  const float* W1   = (const float*)d_in[9];
  const float* b1   = (const float*)d_in[10];
  const float* W2   = (const float*)d_in[11];
  const float* b2   = (const float*)d_in[12];
  const float* bn2g = (const float*)d_in[13];
  const float* bn2b = (const float*)d_in[14];
  float* out = (float*)d_out;

  // residual stream h lives in d_out[0:BND] (fully rewritten every call)
  float* h = out;

  char* wsb = (char*)d_ws;
  ushort* h_hi  = (ushort*)wsb;                     // 13,107,200 B
  ushort* h_lo  = (ushort*)(wsb + 13107200);        // 13,107,200 B
  char*   phase = wsb + 26214400;                   // 104,857,600 B union
  float*  qkv   = (float*)phase;                    //   attn: 78,643,200 B
  ushort* hd_hi = (ushort*)(phase + 78643200);      //   attn: 13,107,200 B
  ushort* hd_lo = (ushort*)(phase + 91750400);      //   attn: 13,107,200 B
  ushort* hid_hi = (ushort*)phase;                  //   ffn: 52,428,800 B
  ushort* hid_lo = (ushort*)(phase + 52428800);     //   ffn: 52,428,800 B
  char*   wp    = wsb + 131072000;
  ushort* qkvT_hi = (ushort*)wp;                    // 294,912 B
  ushort* qkvT_lo = (ushort*)(wp + 294912);
  ushort* woT_hi  = (ushort*)(wp + 589824);         // 98,304 B
  ushort* woT_lo  = (ushort*)(wp + 688128);
  ushort* w1T_hi  = (ushort*)(wp + 786432);         // 393,216 B
  ushort* w1T_lo  = (ushort*)(wp + 1179648);
  ushort* w2T_hi  = (ushort*)(wp + 1572864);        // 393,216 B
  ushort* w2T_lo  = (ushort*)(wp + 1966080);
  float*  psum    = (float*)(wp + 2359296);         // 204,800 B
  float*  psq     = (float*)(wp + 2564096);         // 204,800 B
  float*  scale   = (float*)(wp + 2768896);
  float*  shift   = (float*)(wp + 2769408);

  embed_kernel<<<6400, 256, 0, stream>>>(x, Wemb, bemb, h, h_hi, h_lo);
  t_qkv<<<576, 256, 0, stream>>>(Wq, Wk, Wv, qkvT_hi, qkvT_lo);
  t_wo <<<192, 256, 0, stream>>>(Wo, woT_hi, woT_lo);
  t_w1 <<<768, 256, 0, stream>>>(W1, w1T_hi, w1T_lo);
  t_w2 <<<768, 256, 0, stream>>>(W2, w2T_hi, w2T_lo);

  for (int l = 0; l < L_; l++) {
    const ushort* qkvh = qkvT_hi + l * 49152;
    const ushort* qkvl = qkvT_lo + l * 49152;
    const ushort* woh  = woT_hi  + l * 16384;
    const ushort* wol  = woT_lo  + l * 16384;
    const ushort* w1h  = w1T_hi  + l * 65536;
    const ushort* w1l  = w1T_lo  + l * 65536;
    const ushort* w2h  = w2T_hi  + l * 65536;
    const ushort* w2l  = w2T_lo  + l * 65536;

    // fused QKV projection -> qkv fp32 [rows][384]
    gemm_mfma<128, false, false, false, false, false><<<dim3(3, 400), 256, 0, stream>>>(
        h_hi, h_lo, qkvh, qkvl, nullptr, nullptr, qkv, nullptr, nullptr, nullptr, nullptr, 384);
    // attention -> heads hi/lo
    attn_kernel<<<B_ * H_, 256, 0, stream>>>(qkv, hd_hi, hd_lo);
    // out-proj + residual -> h fp32, + BN1 partial stats
    gemm_mfma<128, false, false, true, false, true><<<dim3(1, 400), 256, 0, stream>>>(
        hd_hi, hd_lo, woh, wol, nullptr, h, h, nullptr, nullptr, psum, psq, 128);
    bn_finalize<<<1, 128, 0, stream>>>(psum, psq, bn1g + l*128, bn1b + l*128, scale, shift);
    bn_apply<<<6400, 256, 0, stream>>>(h, scale, shift, h, h_hi, h_lo);
    // FFN1 + bias + relu -> hidden hi/lo
    gemm_mfma<128, true, true, false, true, false><<<dim3(4, 400), 256, 0, stream>>>(
        h_hi, h_lo, w1h, w1l, b1 + l*512, nullptr, nullptr, hid_hi, hid_lo, nullptr, nullptr, 512);
    // FFN2 + bias + residual -> h fp32, + BN2 partial stats
    gemm_mfma<512, true, false, true, false, true><<<dim3(1, 400), 256, 0, stream>>>(
        hid_hi, hid_lo, w2h, w2l, b2 + l*128, h, h, nullptr, nullptr, psum, psq, 128);
    bn_finalize<<<1, 128, 0, stream>>>(psum, psq, bn2g + l*128, bn2b + l*128, scale, shift);
    bn_apply<<<6400, 256, 0, stream>>>(h, scale, shift, h, h_hi, h_lo);
  }

  mean_kernel<<<B_, 128, 0, stream>>>(out, out + BND);
}